// Round 16
// baseline (372.524 us; speedup 1.0000x reference)
//
#include <hip/hip_runtime.h>
#include <hip/hip_bf16.h>

// Problem constants (static per reference)
#define NN   512    // nodes
#define EE   512    // edges == nb-graph nodes (En)
#define MM   16384  // nb-graph edges

typedef float v4f __attribute__((ext_vector_type(4)));
typedef short short8v __attribute__((ext_vector_type(8)));

__device__ __forceinline__ float silu_f(float v) { return v / (1.0f + __expf(-v)); }
// fast silu: v_rcp_f32 instead of precise division (bf16 data dominates error)
__device__ __forceinline__ float silu_fast(float v) {
  return v * __builtin_amdgcn_rcpf(1.0f + __expf(-v));
}
__device__ __forceinline__ short bf16bits(float x) {
  __hip_bfloat16 b = __float2bfloat16(x);
  return *(short*)&b;
}

// ---------------- K_FRONT: fused {edge MLP, consts, Wt/WBT/W2T prep, mark,
// corr_diag zero, ws-zero} ----------------------------------------------------
// [0,512): edge MLP; 512: c1/c2; [513,577): Wt; [577,705): mark;
// [705,993): WBT; [993,1121): W2T; [1121,1633): corr_diag zero;
// [1633,5158): zero 7,217,680 B at zbase (Tc..corr_col).
__global__ __launch_bounds__(128) void k_front(
    const float* __restrict__ h, const float* __restrict__ x,
    const int* __restrict__ edges, const int* __restrict__ nb_edge,
    const float* __restrict__ ew1, const float* __restrict__ eb1,
    const float* __restrict__ ew2, const float* __restrict__ eb2,
    const float* __restrict__ p1w1, const float* __restrict__ p1b1,
    const float* __restrict__ p1w2, const float* __restrict__ p1b2,
    const float* __restrict__ p2w1, const float* __restrict__ p2b1,
    const float* __restrict__ p2w2, const float* __restrict__ p2b2,
    const float* __restrict__ p3w1,
    float* __restrict__ coord_diff, float* __restrict__ efn,
    float* __restrict__ c1, float* __restrict__ c2,
    __hip_bfloat16* __restrict__ Wt, int* __restrict__ slotmap,
    __hip_bfloat16* __restrict__ WBT, __hip_bfloat16* __restrict__ W2T,
    float* __restrict__ corr_diag, char* __restrict__ zbase) {
  __shared__ float sm[256];
  int b = blockIdx.x, t = threadIdx.x;
  if (b < 512) {
    int r = edges[b], c = edges[EE + b];
    if (t < 3) coord_diff[b * 3 + t] = x[r * 3 + t] - x[c * 3 + t];
    if (t < 64) { sm[t] = h[r * 64 + t]; sm[64 + t] = h[c * 64 + t]; }
    __syncthreads();
    float acc = eb1[t];
    for (int k = 0; k < 128; ++k) acc += sm[k] * ew1[k * 128 + t];
    sm[128 + t] = silu_f(acc);
    __syncthreads();
    if (t < 64) {
      float o = eb2[t];
      for (int k = 0; k < 128; ++k) o += sm[128 + k] * ew2[k * 64 + t];
      efn[b * 64 + t] = o;
    }
  } else if (b == 512) {
    sm[t] = silu_f(p1b1[t]); sm[128 + t] = silu_f(p2b1[t]);
    __syncthreads();
    if (t < 64) {
      float a1 = p1b2[t], a2 = p2b2[t];
      for (int k = 0; k < 128; ++k) { a1 += sm[k] * p1w2[k * 64 + t]; a2 += sm[128 + k] * p2w2[k * 64 + t]; }
      c1[t] = a1; c2[t] = a2;
    }
  } else if (b < 577) {
    int e = (b - 513) * 128 + t;   // 8192 = 128 h x 64 f
    int hh = e >> 6, f = e & 63;
    Wt[hh * 64 + f] = __float2bfloat16(p3w1[(96 + f) * 128 + hh]);
  } else if (b < 705) {
    int m = (b - 577) * 128 + t;   // 16384 nb-edges
    int cell = nb_edge[m] * 512 + nb_edge[MM + m];
    atomicCAS(&slotmap[cell], -1, -2);
  } else if (b < 993) {
    int i = (b - 705) * 128 + t;   // 36864 = 384 n x 96 k
    int n = i / 96, k = i % 96;
    float v = (n < 128) ? p3w1[k * 128 + n]
            : (n < 256) ? p1w1[k * 128 + (n - 128)]
                        : p2w1[k * 128 + (n - 256)];
    WBT[i] = __float2bfloat16(v);
  } else if (b < 1121) {
    int i = (b - 993) * 128 + t;   // 16384 = 2 x 64 n x 128 k
    int which = i >> 13, rem = i & 8191;
    int n = rem >> 7, k = rem & 127;
    const float* w2 = which ? p2w2 : p1w2;
    W2T[i] = __float2bfloat16(w2[k * 64 + n]);
  } else if (b < 1633) {
    ((float4*)corr_diag)[(b - 1121) * 128 + t] = (float4){0.f, 0.f, 0.f, 0.f};
  } else {
    long off = (long)(b - 1633) * 2048 + (long)t * 16;
    if (off < 7217680)
      *(float4*)(zbase + off) = (float4){0.f, 0.f, 0.f, 0.f};
  }
}

// ------ K4: compact marked cells -> slots (ballot-aggregated) ----------------
__global__ __launch_bounds__(256) void k_compact(int* __restrict__ slotmap,
                                                 int* __restrict__ slotmapT,
                                                 int* __restrict__ cells,
                                                 int* __restrict__ nC) {
  __shared__ int wbase[4];
  int cell = blockIdx.x * 256 + threadIdx.x;
  int lane = threadIdx.x & 63;
  int wid = threadIdx.x >> 6;
  bool marked = (slotmap[cell] == -2);
  unsigned long long mask = __ballot(marked);
  if (lane == 0) wbase[wid] = __popcll(mask);
  __syncthreads();
  if (threadIdx.x == 0) {
    int tot = wbase[0] + wbase[1] + wbase[2] + wbase[3];
    int base = tot ? atomicAdd(nC, tot) : 0;
    for (int i = 0; i < 4; ++i) { int c = wbase[i]; wbase[i] = base; base += c; }
  }
  __syncthreads();
  if (marked) {
    int rank = __popcll(mask & ((1ull << lane) - 1ull));
    int s = wbase[wid] + rank;
    slotmap[cell] = s;
    slotmapT[(cell & 511) * 512 + (cell >> 9)] = s;
    cells[s] = cell;
  }
}

// ---------------- K7: nb_feat scatter-add into COMPACT Tc (2 edges/block) ----
__global__ __launch_bounds__(192) void k_scatterT(
    const int* __restrict__ nb_edge, const int* __restrict__ slotmap,
    const float* __restrict__ coord_diff, const float* __restrict__ efn,
    float* __restrict__ Tc) {
  int t = threadIdx.x;
  int sub = (t >= 96) ? 1 : 0;
  int c = t - sub * 96;
  int m = blockIdx.x * 2 + sub;
  int a = nb_edge[m], b = nb_edge[MM + m];
  int s = slotmap[a * 512 + b];
  float val;
  if (c < 32) {
    float vtv = coord_diff[a * 3 + 0] * coord_diff[b * 3 + 0]
              + coord_diff[a * 3 + 1] * coord_diff[b * 3 + 1]
              + coord_diff[a * 3 + 2] * coord_diff[b * 3 + 2];
    int i = c >> 1;
    float ang = vtv * 16.0f * __expf(-0.57564627324851143f * (float)i);
    val = (c & 1) ? cosf(ang) : sinf(ang);
  } else {
    int f = c - 32;
    val = efn[a * 64 + f] * efn[b * 64 + f];
  }
  atomicAdd(&Tc[s * 96 + c], val);
}

// ------- K_GEMM1: [16384 x 96] @ [96 x 384] MFMA, tiles 128x128 --------------
__global__ __launch_bounds__(256) void k_gemm1(
    const int* __restrict__ nC, const float* __restrict__ Tc,
    const __hip_bfloat16* __restrict__ WBT,
    const float* __restrict__ b11, const float* __restrict__ b21,
    float* __restrict__ TWc, __hip_bfloat16* __restrict__ H1,
    __hip_bfloat16* __restrict__ H2) {
  __shared__ short As[128 * 104];
  __shared__ short Bs[128 * 104];
  int i0 = blockIdx.x * 128;
  int nt = blockIdx.y;
  if (i0 >= *nC) return;
  int t = threadIdx.x;
  int w = t >> 6, lane = t & 63;
  int wy = w >> 1, wx = w & 1;
  int q = lane >> 4, l15 = lane & 15;
  const short* Bp = (const short*)WBT + nt * 128 * 96;
  for (int idx = t; idx < 1536; idx += 256) {
    int row = idx / 12, seg = idx % 12;
    const float4* tp = (const float4*)&Tc[(i0 + row) * 96 + seg * 8];
    float4 a0 = tp[0], a1 = tp[1];
    short8v cv = {bf16bits(a0.x), bf16bits(a0.y), bf16bits(a0.z), bf16bits(a0.w),
                  bf16bits(a1.x), bf16bits(a1.y), bf16bits(a1.z), bf16bits(a1.w)};
    *(short8v*)&As[row * 104 + seg * 8] = cv;
    *(short8v*)&Bs[row * 104 + seg * 8] = *(const short8v*)&Bp[row * 96 + seg * 8];
  }
  __syncthreads();
  v4f acc[4][4];
#pragma unroll
  for (int yi = 0; yi < 4; ++yi)
#pragma unroll
    for (int xj = 0; xj < 4; ++xj) acc[yi][xj] = (v4f){0.f, 0.f, 0.f, 0.f};
#pragma unroll
  for (int k0 = 0; k0 < 96; k0 += 32) {
    short8v af[4], bf[4];
#pragma unroll
    for (int x = 0; x < 4; ++x) {
      af[x] = *(const short8v*)&As[(wy * 64 + x * 16 + l15) * 104 + k0 + q * 8];
      bf[x] = *(const short8v*)&Bs[(wx * 64 + x * 16 + l15) * 104 + k0 + q * 8];
    }
#pragma unroll
    for (int yi = 0; yi < 4; ++yi)
#pragma unroll
      for (int xj = 0; xj < 4; ++xj)
        acc[yi][xj] = __builtin_amdgcn_mfma_f32_16x16x32_bf16(af[yi], bf[xj], acc[yi][xj], 0, 0, 0);
  }
  // C layout [m89]: row = q*4+r, col = l15
#pragma unroll
  for (int yi = 0; yi < 4; ++yi)
#pragma unroll
    for (int r = 0; r < 4; ++r) {
      int s = i0 + wy * 64 + yi * 16 + q * 4 + r;
#pragma unroll
      for (int xj = 0; xj < 4; ++xj) {
        int j = wx * 64 + xj * 16 + l15;
        float val = acc[yi][xj][r];
        if (nt == 0) TWc[s * 128 + j] = val;
        else if (nt == 1) H1[s * 128 + j] = __float2bfloat16(silu_f(val + b11[j]));
        else H2[s * 128 + j] = __float2bfloat16(silu_f(val + b21[j]));
      }
    }
}

// ------- K_GEMM2: [16384 x 128] @ [128 x 64] MFMA, tiles 128x64 --------------
__global__ __launch_bounds__(256) void k_gemm2(
    const int* __restrict__ nC, const int* __restrict__ cells,
    const __hip_bfloat16* __restrict__ H1, const __hip_bfloat16* __restrict__ H2,
    const __hip_bfloat16* __restrict__ W2T,
    const float* __restrict__ b12, const float* __restrict__ b22,
    const float* __restrict__ c1, const float* __restrict__ c2,
    __hip_bfloat16* __restrict__ Dc1, __hip_bfloat16* __restrict__ Dc2,
    float* __restrict__ A, float* __restrict__ B) {
  __shared__ short Hs[128 * 136];   // 34,816 B
  __shared__ short Wsh[64 * 136];   // 17,408 B
  __shared__ int cellL[128];
  int i0 = blockIdx.x * 128;
  int which = blockIdx.y;
  int nc = *nC;
  if (i0 >= nc) return;
  int t = threadIdx.x;
  int w = t >> 6, lane = t & 63;
  int q = lane >> 4, l15 = lane & 15;
  const short* Hp = (const short*)(which ? H2 : H1);
  const short* Wp = (const short*)W2T + which * 64 * 128;
  for (int idx = t; idx < 2048; idx += 256) {
    int row = idx >> 4, seg = idx & 15;
    *(short8v*)&Hs[row * 136 + seg * 8] = *(const short8v*)&Hp[(i0 + row) * 128 + seg * 8];
  }
  for (int idx = t; idx < 1024; idx += 256) {
    int row = idx >> 4, seg = idx & 15;
    *(short8v*)&Wsh[row * 136 + seg * 8] = *(const short8v*)&Wp[row * 128 + seg * 8];
  }
  if (t < 128) cellL[t] = (i0 + t < nc) ? cells[i0 + t] : 0;
  __syncthreads();
  v4f acc[2][4];
#pragma unroll
  for (int y = 0; y < 2; ++y)
#pragma unroll
    for (int xj = 0; xj < 4; ++xj) acc[y][xj] = (v4f){0.f, 0.f, 0.f, 0.f};
#pragma unroll
  for (int k0 = 0; k0 < 128; k0 += 32) {
    short8v af[2], bf[4];
#pragma unroll
    for (int y = 0; y < 2; ++y)
      af[y] = *(const short8v*)&Hs[(w * 32 + y * 16 + l15) * 136 + k0 + q * 8];
#pragma unroll
    for (int xj = 0; xj < 4; ++xj)
      bf[xj] = *(const short8v*)&Wsh[(xj * 16 + l15) * 136 + k0 + q * 8];
#pragma unroll
    for (int y = 0; y < 2; ++y)
#pragma unroll
      for (int xj = 0; xj < 4; ++xj)
        acc[y][xj] = __builtin_amdgcn_mfma_f32_16x16x32_bf16(af[y], bf[xj], acc[y][xj], 0, 0, 0);
  }
  const float* bias = which ? b22 : b12;
  const float* cc = which ? c2 : c1;
#pragma unroll
  for (int y = 0; y < 2; ++y)
#pragma unroll
    for (int r = 0; r < 4; ++r) {
      int lrow = w * 32 + y * 16 + q * 4 + r;
      int s = i0 + lrow;
      if (s >= nc) continue;
      int cell = cellL[lrow];
      int idx = which ? (cell & 511) : (cell >> 9);
#pragma unroll
      for (int xj = 0; xj < 4; ++xj) {
        int hh = xj * 16 + l15;
        float d = acc[y][xj][r] + bias[hh] - cc[hh];
        if (which) { atomicAdd(&B[idx * 64 + hh], d); Dc2[s * 64 + hh] = __float2bfloat16(d); }
        else       { atomicAdd(&A[idx * 64 + hh], d); Dc1[s * 64 + hh] = __float2bfloat16(d); }
      }
    }
}

// ------- K_DENS_UV: fused {densify planes, u/v vectors} ----------------------
__global__ __launch_bounds__(128) void k_dens_uv(
    const int* __restrict__ slotmap, const int* __restrict__ slotmapT,
    const __hip_bfloat16* __restrict__ Dc1, const __hip_bfloat16* __restrict__ Dc2,
    __hip_bfloat16* __restrict__ D1d, __hip_bfloat16* __restrict__ D2dT,
    const float* __restrict__ A, const float* __restrict__ B,
    const float* __restrict__ c1, const float* __restrict__ c2,
    const float* __restrict__ p3w1, const float* __restrict__ p3b1,
    float* __restrict__ u, float* __restrict__ v) {
  __shared__ float vec[64];
  int b = blockIdx.x, t = threadIdx.x;
  if (b < 65536) {
    int which = b >> 15, bb = b & 32767;
    int f = bb >> 9, row = bb & 511;
    const int* sm = which ? &slotmapT[row * 512] : &slotmap[row * 512];
    const unsigned short* Dc = (const unsigned short*)(which ? Dc2 : Dc1);
    unsigned short* dst = (unsigned short*)(which ? &D2dT[(f * 512 + row) * 512]
                                                  : &D1d[(f * 512 + row) * 512]);
    int4 s4 = *(const int4*)&sm[t * 4];
    ushort4 o;
    o.x = (s4.x >= 0) ? Dc[s4.x * 64 + f] : 0;
    o.y = (s4.y >= 0) ? Dc[s4.y * 64 + f] : 0;
    o.z = (s4.z >= 0) ? Dc[s4.z * 64 + f] : 0;
    o.w = (s4.w >= 0) ? Dc[s4.w * 64 + f] : 0;
    *(ushort4*)&dst[t * 4] = o;
  } else {
    int e = b - 65536;
    int i = e >> 1, y = e & 1;
    if (t < 64)
      vec[t] = (y == 0) ? (512.0f * c1[t] * c2[t] + c2[t] * A[i * 64 + t])
                        : (c1[t] * B[i * 64 + t]);
    __syncthreads();
    float a = (y == 0) ? p3b1[t] : 0.f;
    for (int f = 0; f < 64; ++f) a += vec[f] * p3w1[(96 + f) * 128 + t];
    (y == 0 ? u : v)[i * 128 + t] = a;
  }
}

// ---------------- K11b: batched plane GEMM S_f = A_f * B_f (MFMA) ------------
// XCD-aware bijective swizzle (proven v11): each XCD owns 8 whole planes.
__global__ __launch_bounds__(256) void k_einsum_mfma(
    const __hip_bfloat16* __restrict__ D1d,
    const __hip_bfloat16* __restrict__ D2dT,
    __hip_bfloat16* __restrict__ S_fij) {
  __shared__ short As[128 * 40];
  __shared__ short Bs[128 * 40];
  int braw = blockIdx.x;
  int b = (braw & 7) * 128 + (braw >> 3);   // bijective XCD swizzle (1024 = 8*128)
  int f = b >> 4;
  int i0 = ((b >> 2) & 3) * 128, j0 = (b & 3) * 128;
  int t = threadIdx.x;
  int w = t >> 6, lane = t & 63;
  int wy = w >> 1, wx = w & 1;
  int q = lane >> 4, l15 = lane & 15;
  const short* Ap = (const short*)D1d + f * 262144;
  const short* Bp = (const short*)D2dT + f * 262144;
  int row = t >> 1, seg = t & 1;   // staging: 128 rows x 2 segments of 16
  v4f acc[4][4];
#pragma unroll
  for (int yi = 0; yi < 4; ++yi)
#pragma unroll
    for (int xj = 0; xj < 4; ++xj) acc[yi][xj] = (v4f){0.f, 0.f, 0.f, 0.f};
  for (int k0 = 0; k0 < 512; k0 += 32) {
    __syncthreads();
    const short8v* ga = (const short8v*)&Ap[(i0 + row) * 512 + k0 + seg * 16];
    const short8v* gb = (const short8v*)&Bp[(j0 + row) * 512 + k0 + seg * 16];
    *(short8v*)&As[row * 40 + seg * 16] = ga[0];
    *(short8v*)&As[row * 40 + seg * 16 + 8] = ga[1];
    *(short8v*)&Bs[row * 40 + seg * 16] = gb[0];
    *(short8v*)&Bs[row * 40 + seg * 16 + 8] = gb[1];
    __syncthreads();
    short8v af[4], bf[4];
#pragma unroll
    for (int x = 0; x < 4; ++x) {
      af[x] = *(const short8v*)&As[(wy * 64 + x * 16 + l15) * 40 + q * 8];
      bf[x] = *(const short8v*)&Bs[(wx * 64 + x * 16 + l15) * 40 + q * 8];
    }
#pragma unroll
    for (int yi = 0; yi < 4; ++yi)
#pragma unroll
      for (int xj = 0; xj < 4; ++xj)
        acc[yi][xj] = __builtin_amdgcn_mfma_f32_16x16x32_bf16(af[yi], bf[xj], acc[yi][xj], 0, 0, 0);
  }
  // C layout: col j = l15, row i = q*4 + r  [m89-verified]
#pragma unroll
  for (int yi = 0; yi < 4; ++yi)
#pragma unroll
    for (int r = 0; r < 4; ++r) {
      int irow = i0 + wy * 64 + yi * 16 + q * 4 + r;
#pragma unroll
      for (int xj = 0; xj < 4; ++xj)
        S_fij[(f * 512 + irow) * 512 + j0 + wx * 64 + xj * 16 + l15] =
            __float2bfloat16(acc[yi][xj][r]);
    }
}

// ---------------- K11c: transpose S_fij [64][262144] -> S [262144][64] -------
__global__ __launch_bounds__(256) void k_transpose(
    const __hip_bfloat16* __restrict__ S_fij, __hip_bfloat16* __restrict__ S) {
  __shared__ short lds[64 * 72];
  int t = threadIdx.x;
  int ij0 = blockIdx.x * 64;
  const short* src = (const short*)S_fij;
#pragma unroll
  for (int p = 0; p < 2; ++p) {
    int f = p * 32 + (t >> 3), seg = t & 7;
    short8v ga = *(const short8v*)&src[f * 262144 + ij0 + seg * 8];
    int fgrp = f >> 3, flo = f & 7;
#pragma unroll
    for (int k = 0; k < 8; ++k) {
      int ij = seg * 8 + k;
      int swz = (fgrp ^ (ij & 7) ^ ((ij >> 3) & 7)) & 7;
      lds[ij * 72 + swz * 8 + flo] = ga[k];
    }
  }
  __syncthreads();
  short* dst = (short*)S;
#pragma unroll
  for (int p = 0; p < 2; ++p) {
    int ij = p * 32 + (t >> 3), fseg = t & 7;
    int swz = (fseg ^ (ij & 7) ^ ((ij >> 3) & 7)) & 7;
    short8v val = *(const short8v*)&lds[ij * 72 + swz * 8];
    *(short8v*)&dst[(ij0 + ij) * 64 + fseg * 8] = val;
  }
}

// ------- K12: dense MFMA z = S@Wt + u[i]+v[j], silu, row/col/diag reduce -----
// v13: row/col sums atomicAdd DIRECTLY into corr_row/corr_col (zeroed
// accumulators shared with k_corr) -> row_part/col_part arrays deleted
// (saves ~33 MB round-trip + tout2f's 32-iter reduce).
__global__ __launch_bounds__(256) void k_tout_mfma(
    const __hip_bfloat16* __restrict__ S, const float* __restrict__ u,
    const float* __restrict__ v, const __hip_bfloat16* __restrict__ Wt,
    float* __restrict__ corr_row, float* __restrict__ corr_col,
    float* __restrict__ diag_silu) {
  __shared__ __hip_bfloat16 WtL[128 * 72];         // 18,432 B
  __shared__ __hip_bfloat16 uvL[4096];             // 8,192 B
  __shared__ __hip_bfloat16 colbuf[4][16][140];    // 17,920 B
  int t = threadIdx.x;
  int w = t >> 6, lane = t & 63;
  int q = lane >> 4, l15 = lane & 15;
  int bi = blockIdx.x >> 5, bj = blockIdx.x & 31;
  int i0 = bi * 16, j0 = bj * 16;
  for (int e = t; e < 4096; e += 256) {
    int row = e >> 5, c2 = e & 31;
    ((unsigned*)WtL)[row * 36 + c2] = ((const unsigned*)Wt)[row * 32 + c2];
  }
  for (int e = t; e < 2048; e += 256)
    uvL[e] = __float2bfloat16(u[(i0 + (e >> 7)) * 128 + (e & 127)]);
  for (int e = t; e < 2048; e += 256)
    uvL[2048 + e] = __float2bfloat16(v[(j0 + (e >> 7)) * 128 + (e & 127)]);
  short8v a[4][2];
#pragma unroll
  for (int mt = 0; mt < 4; ++mt) {
    const short8v* sp =
        (const short8v*)&S[((i0 + w * 4 + mt) * 512 + j0 + l15) * 64];
    a[mt][0] = sp[q];
    a[mt][1] = sp[4 + q];
  }
  __syncthreads();
#pragma unroll
  for (int half = 0; half < 2; ++half) {
    v4f acc[4][4];
#pragma unroll
    for (int mt = 0; mt < 4; ++mt)
#pragma unroll
      for (int n4 = 0; n4 < 4; ++n4) {
        int nt = half * 4 + n4;
        const short8v* b0 = (const short8v*)&WtL[(nt * 16 + l15) * 72 + q * 8];
        const short8v* b1 = (const short8v*)&WtL[(nt * 16 + l15) * 72 + 32 + q * 8];
        v4f c = {0.f, 0.f, 0.f, 0.f};
        c = __builtin_amdgcn_mfma_f32_16x16x32_bf16(a[mt][0], *b0, c, 0, 0, 0);
        c = __builtin_amdgcn_mfma_f32_16x16x32_bf16(a[mt][1], *b1, c, 0, 0, 0);
        acc[mt][n4] = c;
      }
#pragma unroll
    for (int n4 = 0; n4 < 4; ++n4) {
      int nt = half * 4 + n4;
      int hh = nt * 16 + l15;
      float uu[4];
#pragma unroll
      for (int mt = 0; mt < 4; ++mt)
        uu[mt] = __bfloat162float(uvL[(w * 4 + mt) * 128 + hh]);
      float rs[4] = {0.f, 0.f, 0.f, 0.f};
#pragma unroll
      for (int r = 0; r < 4; ++r) {
        int jL = q * 4 + r;
        float cs = 0.f;
        float vv = __bfloat162float(uvL[2048 + jL * 128 + hh]);
#pragma unroll
        for (int mt = 0; mt < 4; ++mt) {
          int iL = w * 4 + mt;
          float sv = silu_fast(acc[mt][n4][r] + uu[mt] + vv);
          rs[mt] += sv;
          cs += sv;
          if (bi == bj && iL == jL) diag_silu[(i0 + iL) * 128 + hh] = sv;
        }
        colbuf[w][jL][hh] = __float2bfloat16(cs);
      }
#pragma unroll
      for (int mt = 0; mt < 4; ++mt) {
        float rsum = rs[mt];
        rsum += __shfl_xor(rsum, 16);
        rsum += __shfl_xor(rsum, 32);
        if (q == 0)
          atomicAdd(&corr_row[(i0 + w * 4 + mt) * 128 + hh], rsum);
      }
    }
  }
  __syncthreads();
  for (int e = t; e < 2048; e += 256) {
    int jL = e >> 7, hh = e & 127;
    float acc4 = __bfloat162float(colbuf[0][jL][hh]) + __bfloat162float(colbuf[1][jL][hh]) +
                 __bfloat162float(colbuf[2][jL][hh]) + __bfloat162float(colbuf[3][jL][hh]);
    atomicAdd(&corr_col[(j0 + jL) * 128 + hh], acc4);
  }
}

// ------- K_CORR: sparse TW correction at touched cells (standalone) ----------
__global__ __launch_bounds__(128) void k_corr(
    const int* __restrict__ cells, const int* __restrict__ nC,
    const __hip_bfloat16* __restrict__ S, const float* __restrict__ u,
    const float* __restrict__ v, const float* __restrict__ TWc,
    const __hip_bfloat16* __restrict__ Wt,
    float* __restrict__ corr_row, float* __restrict__ corr_col,
    float* __restrict__ corr_diag) {
  __shared__ float sf[64];
  int s = blockIdx.x;
  if (s >= *nC) return;
  int t = threadIdx.x;
  int cell = cells[s];
  int ai = cell >> 9, bj = cell & 511;
  if (t < 64) sf[t] = __bfloat162float(S[(ai * 512 + bj) * 64 + t]);
  __syncthreads();
  float acc = 0.f;
  const __hip_bfloat16* wr = &Wt[t * 64];
  for (int f = 0; f < 64; ++f) acc += sf[f] * __bfloat162float(wr[f]);
  float z0 = acc + u[ai * 128 + t] + v[bj * 128 + t];
  float zc = z0 + TWc[s * 128 + t];
  float d = silu_fast(zc) - silu_fast(z0);
  atomicAdd(&corr_row[ai * 128 + t], d);
  atomicAdd(&corr_col[bj * 128 + t], d);
  if (ai == bj) atomicAdd(&corr_diag[ai * 128 + t], d);
}

// ------- K_TOUT2F: {p3 layer-2 matvec on accumulated sums, tot/tr} -----------
__global__ __launch_bounds__(128) void k_tout2f(
    const float* __restrict__ diag_silu,
    const float* __restrict__ corr_row, const float* __restrict__ corr_col,
    const float* __restrict__ corr_diag,
    const float* __restrict__ w2, const float* __restrict__ b2,
    float* __restrict__ diag_T, float* __restrict__ row_T, float* __restrict__ col_T,
    float* __restrict__ tot, float* __restrict__ tr) {
  __shared__ float in[128];
  int e = blockIdx.x, which = blockIdx.y, t = threadIdx.x;
  float a;
  if (which == 0)      a = diag_silu[e * 128 + t] + corr_diag[e * 128 + t];
  else if (which == 1) a = corr_row[e * 128 + t];
  else                 a = corr_col[e * 128 + t];
  in[t] = a;
  __syncthreads();
  if (t < 64) {
    float o = 0.f;
    for (int k = 0; k < 128; ++k) o += in[k] * w2[k * 64 + t];
    float val = o + b2[t] * ((which == 0) ? 1.0f : 512.0f);
    if (which == 0)      { diag_T[e * 64 + t] = val; atomicAdd(&tr[t], val); }
    else if (which == 1) { row_T[e * 64 + t] = val; atomicAdd(&tot[t], val); }
    else                 { col_T[e * 64 + t] = val; }
  }
}

// ------- K_NBT1_EDGE: fused {IGN linear, coord weight, seg/cnt/nb_t0} --------
__global__ __launch_bounds__(128) void k_nbt1_edge(
    const float* __restrict__ diag_T, const float* __restrict__ row_T,
    const float* __restrict__ col_T, const float* __restrict__ tot,
    const float* __restrict__ tr,
    const float* __restrict__ gw, const float* __restrict__ gb,
    const int* __restrict__ edges, const float* __restrict__ coord_diff,
    const float* __restrict__ edge_attr,
    const float* __restrict__ cw1, const float* __restrict__ cb1,
    const float* __restrict__ cw2,
    float* __restrict__ seg, float* __restrict__ cnt, float* __restrict__ nb_t0,
    float* __restrict__ out_ea) {
  __shared__ float in[320];
  __shared__ float nbt[64];
  __shared__ float red[128];
  int e = blockIdx.x, t = threadIdx.x;
  if (t < 64) {
    in[t] = diag_T[e * 64 + t]; in[64 + t] = row_T[e * 64 + t];
    in[128 + t] = col_T[e * 64 + t]; in[192 + t] = tot[t]; in[256 + t] = tr[t];
  }
  __syncthreads();
  if (t < 64) {
    float a = gb[t];
    for (int k = 0; k < 320; ++k) a += in[k] * gw[k * 64 + t];
    nbt[t] = a;
  }
  __syncthreads();
  float a = cb1[t];
  for (int k = 0; k < 64; ++k) a += nbt[k] * cw1[k * 128 + t];
  red[t] = silu_f(a) * cw2[t];
  __syncthreads();
  for (int s2 = 64; s2 > 0; s2 >>= 1) {
    if (t < s2) red[t] += red[t + s2];
    __syncthreads();
  }
  float w = red[0];
  int r = edges[e];
  if (t < 3) atomicAdd(&seg[r * 3 + t], coord_diff[e * 3 + t] * w);
  if (t == 64) atomicAdd(&cnt[r], 1.0f);
  if (t < 64) atomicAdd(&nb_t0[r * 64 + t], nbt[t]);
  if (t < 4) out_ea[e * 4 + t] = edge_attr[e * 4 + t];
}

// ---------------- K18: x_new and h_new ---------------------------------------
__global__ __launch_bounds__(128) void k_node_out(
    const float* __restrict__ h, const float* __restrict__ x,
    const float* __restrict__ seg, const float* __restrict__ cnt,
    const float* __restrict__ nb_t0,
    const float* __restrict__ w1, const float* __restrict__ b1,
    const float* __restrict__ w2, const float* __restrict__ b2,
    float* __restrict__ out_h, float* __restrict__ out_x) {
  __shared__ float in[64];
  __shared__ float hs[128];
  int n = blockIdx.x, t = threadIdx.x;
  if (t < 3) {
    float c = cnt[n]; if (c < 1.f) c = 1.f;
    out_x[n * 3 + t] = x[n * 3 + t] + seg[n * 3 + t] / c;
  }
  if (t < 64) in[t] = nb_t0[n * 64 + t];
  __syncthreads();
  float a = b1[t];
  for (int k = 0; k < 64; ++k) a += in[k] * w1[k * 128 + t];
  hs[t] = silu_f(a);
  __syncthreads();
  if (t < 64) {
    float o = b2[t];
    for (int k = 0; k < 128; ++k) o += hs[k] * w2[k * 64 + t];
    out_h[n * 64 + t] = h[n * 64 + t] + o;
  }
}

extern "C" void kernel_launch(void* const* d_in, const int* in_sizes, int n_in,
                              void* d_out, int out_size, void* d_ws, size_t ws_size,
                              hipStream_t stream) {
  (void)in_sizes; (void)n_in; (void)out_size; (void)ws_size;
  const float* h  = (const float*)d_in[0];
  const float* x  = (const float*)d_in[1];
  const int* edges   = (const int*)d_in[2];
  const int* nb_edge = (const int*)d_in[3];
  const float* edge_attr = (const float*)d_in[4];
  const float* ew1 = (const float*)d_in[6],  *eb1 = (const float*)d_in[7];
  const float* ew2 = (const float*)d_in[8],  *eb2 = (const float*)d_in[9];
  const float* p1w1 = (const float*)d_in[10], *p1b1 = (const float*)d_in[11];
  const float* p1w2 = (const float*)d_in[12], *p1b2 = (const float*)d_in[13];
  const float* p2w1 = (const float*)d_in[14], *p2b1 = (const float*)d_in[15];
  const float* p2w2 = (const float*)d_in[16], *p2b2 = (const float*)d_in[17];
  const float* p3w1 = (const float*)d_in[18], *p3b1 = (const float*)d_in[19];
  const float* p3w2 = (const float*)d_in[20], *p3b2 = (const float*)d_in[21];
  const float* ignw = (const float*)d_in[22], *ignb = (const float*)d_in[23];
  const float* cw1 = (const float*)d_in[24], *cb1 = (const float*)d_in[25];
  const float* cw2 = (const float*)d_in[26];
  const float* ndw1 = (const float*)d_in[27], *ndb1 = (const float*)d_in[28];
  const float* ndw2 = (const float*)d_in[29], *ndb2 = (const float*)d_in[30];

  // ---- workspace layout (~157.9 MB) ----
  char* ws = (char*)d_ws;
  __hip_bfloat16* D1d  = (__hip_bfloat16*)(ws + 0);          // [64][512][512] = 33,554,432 B
  __hip_bfloat16* S    = (__hip_bfloat16*)(ws + 0);          // cell-major S aliases dead D1d
  __hip_bfloat16* D2dT = (__hip_bfloat16*)(ws + 33554432);   // 33,554,432 B
  __hip_bfloat16* S_fij = (__hip_bfloat16*)(ws + 67108864);  // 33,554,432 B
  // GEMM scratch aliases the S_fij region (dead until k_einsum):
  __hip_bfloat16* H1  = (__hip_bfloat16*)(ws + 70254592);    // [16384][128] = 4,194,304 B
  __hip_bfloat16* H2  = (__hip_bfloat16*)(ws + 74448896);    // 4,194,304 B
  __hip_bfloat16* WBT = (__hip_bfloat16*)(ws + 78643200);    // [384][96] = 73,728 B
  __hip_bfloat16* W2T = (__hip_bfloat16*)(ws + 78716928);    // [2][64][128] = 32,768 B
  // ---- single zero block [134,217,728 .. 141,435,408), zeroed by k_front ----
  float* Tc    = (float*)(ws + 134217728);                   // [16384][96] = 6,291,456 B
  int*   nC    = (int*)(ws + 140509184);                     // 1 int (+pad to 16)
  float* A     = (float*)(ws + 140509200);                   // 32768 floats
  float* B     = (float*)(ws + 140640272);                   // 32768 floats
  float* seg   = (float*)(ws + 140771344);                   // 1536 floats
  float* cnt   = (float*)(ws + 140777488);                   // 512 floats
  float* nb_t0 = (float*)(ws + 140779536);                   // 32768 floats -> 140,910,608
  float* tot   = (float*)(ws + 140910608);                   // 64 floats
  float* tr    = (float*)(ws + 140910864);                   // 64 floats -> 140,911,120
  float* corr_row = (float*)(ws + 140911120);                // [512][128] -> 141,173,264
  float* corr_col = (float*)(ws + 141173264);                // [512][128] -> 141,435,408
  // ---- 0xFF block: slotmap + slotmapT (2 MB contiguous) ----
  int*   slotmap  = (int*)(ws + 141435904);                  // 262144 ints
  int*   slotmapT = (int*)(ws + 142484480);                  // 262144 ints
  // ---- rest ----
  int*   cells    = (int*)(ws + 143533056);                  // 16384 ints
  __hip_bfloat16* Dc1 = (__hip_bfloat16*)(ws + 143598592);   // [16384][64] = 2,097,152 B
  __hip_bfloat16* Dc2 = (__hip_bfloat16*)(ws + 145695744);   // 2,097,152 B
  float* TWc      = (float*)(ws + 147792896);                // [16384][128]
  float* c1       = (float*)(ws + 156181504);                // 64
  float* c2       = (float*)(ws + 156181760);                // 64
  float* u        = (float*)(ws + 156182016);                // [512][128]
  float* v        = (float*)(ws + 156444160);                // [512][128]
  float* coord_diff  = (float*)(ws + 156706304);             // [512][3]
  float* efn         = (float*)(ws + 156712448);             // [512][64]
  float* diag_silu   = (float*)(ws + 156843520);             // [512][128]
  float* diag_T      = (float*)(ws + 157105664);             // [512][64]
  float* row_T       = (float*)(ws + 157236736);
  float* col_T       = (float*)(ws + 157367808);
  __hip_bfloat16* Wt  = (__hip_bfloat16*)(ws + 157629952);   // [128][64] -> 157,646,336
  float* corr_diag   = (float*)(ws + 157646336);             // [512][128] (zeroed by k_front)

  float* out_h  = (float*)d_out;
  float* out_x  = out_h + 512 * 64;
  float* out_ea = out_x + 512 * 3;

  hipMemsetAsync(slotmap, 0xFF, 2097152, stream);            // slotmap + slotmapT = -1

  k_front<<<5158, 128, 0, stream>>>(h, x, edges, nb_edge,
                                    ew1, eb1, ew2, eb2,
                                    p1w1, p1b1, p1w2, p1b2,
                                    p2w1, p2b1, p2w2, p2b2, p3w1,
                                    coord_diff, efn, c1, c2, Wt, slotmap,
                                    WBT, W2T, corr_diag, ws + 134217728);
  k_compact<<<1024, 256, 0, stream>>>(slotmap, slotmapT, cells, nC);
  k_scatterT<<<8192, 192, 0, stream>>>(nb_edge, slotmap, coord_diff, efn, Tc);
  k_gemm1<<<dim3(128, 3), 256, 0, stream>>>(nC, Tc, WBT, p1b1, p2b1,
                                            TWc, H1, H2);
  k_gemm2<<<dim3(128, 2), 256, 0, stream>>>(nC, cells, H1, H2, W2T,
                                            p1b2, p2b2, c1, c2,
                                            Dc1, Dc2, A, B);
  k_dens_uv<<<66560, 128, 0, stream>>>(slotmap, slotmapT, Dc1, Dc2, D1d, D2dT,
                                       A, B, c1, c2, p3w1, p3b1, u, v);
  k_einsum_mfma<<<1024, 256, 0, stream>>>(D1d, D2dT, S_fij);
  k_transpose<<<4096, 256, 0, stream>>>(S_fij, S);
  k_tout_mfma<<<1024, 256, 0, stream>>>(S, u, v, Wt,
                                        corr_row, corr_col, diag_silu);
  k_corr<<<16384, 128, 0, stream>>>(cells, nC, S, u, v, TWc, Wt,
                                    corr_row, corr_col, corr_diag);
  k_tout2f<<<dim3(512, 3), 128, 0, stream>>>(diag_silu,
                                             corr_row, corr_col, corr_diag,
                                             p3w2, p3b2, diag_T, row_T, col_T,
                                             tot, tr);
  k_nbt1_edge<<<512, 128, 0, stream>>>(diag_T, row_T, col_T, tot, tr,
                                       ignw, ignb, edges, coord_diff, edge_attr,
                                       cw1, cb1, cw2, seg, cnt, nb_t0, out_ea);
  k_node_out<<<512, 128, 0, stream>>>(h, x, seg, cnt, nb_t0,
                                      ndw1, ndb1, ndw2, ndb2, out_h, out_x);
}

// Round 17
// 360.900 us; speedup vs baseline: 1.0322x; 1.0322x over previous
//
#include <hip/hip_runtime.h>
#include <hip/hip_bf16.h>

// Problem constants (static per reference)
#define NN   512    // nodes
#define EE   512    // edges == nb-graph nodes (En)
#define MM   16384  // nb-graph edges

typedef float v4f __attribute__((ext_vector_type(4)));
typedef short short8v __attribute__((ext_vector_type(8)));

__device__ __forceinline__ float silu_f(float v) { return v / (1.0f + __expf(-v)); }
// fast silu: v_rcp_f32 instead of precise division (bf16 data dominates error)
__device__ __forceinline__ float silu_fast(float v) {
  return v * __builtin_amdgcn_rcpf(1.0f + __expf(-v));
}
__device__ __forceinline__ short bf16bits(float x) {
  __hip_bfloat16 b = __float2bfloat16(x);
  return *(short*)&b;
}

// ---------------- K_FRONT: fused {edge MLP, consts, Wt/WBT/W2T prep, mark,
// corr_diag zero, ws-zero} ----------------------------------------------------
// [0,512): edge MLP; 512: c1/c2; [513,577): Wt; [577,705): mark;
// [705,993): WBT; [993,1121): W2T; [1121,1633): corr_diag zero;
// [1633,5158): zero 7,217,680 B at zbase (Tc..corr_col).
__global__ __launch_bounds__(128) void k_front(
    const float* __restrict__ h, const float* __restrict__ x,
    const int* __restrict__ edges, const int* __restrict__ nb_edge,
    const float* __restrict__ ew1, const float* __restrict__ eb1,
    const float* __restrict__ ew2, const float* __restrict__ eb2,
    const float* __restrict__ p1w1, const float* __restrict__ p1b1,
    const float* __restrict__ p1w2, const float* __restrict__ p1b2,
    const float* __restrict__ p2w1, const float* __restrict__ p2b1,
    const float* __restrict__ p2w2, const float* __restrict__ p2b2,
    const float* __restrict__ p3w1,
    float* __restrict__ coord_diff, float* __restrict__ efn,
    float* __restrict__ c1, float* __restrict__ c2,
    __hip_bfloat16* __restrict__ Wt, int* __restrict__ slotmap,
    __hip_bfloat16* __restrict__ WBT, __hip_bfloat16* __restrict__ W2T,
    float* __restrict__ corr_diag, char* __restrict__ zbase) {
  __shared__ float sm[256];
  int b = blockIdx.x, t = threadIdx.x;
  if (b < 512) {
    int r = edges[b], c = edges[EE + b];
    if (t < 3) coord_diff[b * 3 + t] = x[r * 3 + t] - x[c * 3 + t];
    if (t < 64) { sm[t] = h[r * 64 + t]; sm[64 + t] = h[c * 64 + t]; }
    __syncthreads();
    float acc = eb1[t];
    for (int k = 0; k < 128; ++k) acc += sm[k] * ew1[k * 128 + t];
    sm[128 + t] = silu_f(acc);
    __syncthreads();
    if (t < 64) {
      float o = eb2[t];
      for (int k = 0; k < 128; ++k) o += sm[128 + k] * ew2[k * 64 + t];
      efn[b * 64 + t] = o;
    }
  } else if (b == 512) {
    sm[t] = silu_f(p1b1[t]); sm[128 + t] = silu_f(p2b1[t]);
    __syncthreads();
    if (t < 64) {
      float a1 = p1b2[t], a2 = p2b2[t];
      for (int k = 0; k < 128; ++k) { a1 += sm[k] * p1w2[k * 64 + t]; a2 += sm[128 + k] * p2w2[k * 64 + t]; }
      c1[t] = a1; c2[t] = a2;
    }
  } else if (b < 577) {
    int e = (b - 513) * 128 + t;   // 8192 = 128 h x 64 f
    int hh = e >> 6, f = e & 63;
    Wt[hh * 64 + f] = __float2bfloat16(p3w1[(96 + f) * 128 + hh]);
  } else if (b < 705) {
    int m = (b - 577) * 128 + t;   // 16384 nb-edges
    int cell = nb_edge[m] * 512 + nb_edge[MM + m];
    atomicCAS(&slotmap[cell], -1, -2);
  } else if (b < 993) {
    int i = (b - 705) * 128 + t;   // 36864 = 384 n x 96 k
    int n = i / 96, k = i % 96;
    float v = (n < 128) ? p3w1[k * 128 + n]
            : (n < 256) ? p1w1[k * 128 + (n - 128)]
                        : p2w1[k * 128 + (n - 256)];
    WBT[i] = __float2bfloat16(v);
  } else if (b < 1121) {
    int i = (b - 993) * 128 + t;   // 16384 = 2 x 64 n x 128 k
    int which = i >> 13, rem = i & 8191;
    int n = rem >> 7, k = rem & 127;
    const float* w2 = which ? p2w2 : p1w2;
    W2T[i] = __float2bfloat16(w2[k * 64 + n]);
  } else if (b < 1633) {
    ((float4*)corr_diag)[(b - 1121) * 128 + t] = (float4){0.f, 0.f, 0.f, 0.f};
  } else {
    long off = (long)(b - 1633) * 2048 + (long)t * 16;
    if (off < 7217680)
      *(float4*)(zbase + off) = (float4){0.f, 0.f, 0.f, 0.f};
  }
}

// ------ K4: compact marked cells -> slots (ballot-aggregated) ----------------
__global__ __launch_bounds__(256) void k_compact(int* __restrict__ slotmap,
                                                 int* __restrict__ slotmapT,
                                                 int* __restrict__ cells,
                                                 int* __restrict__ nC) {
  __shared__ int wbase[4];
  int cell = blockIdx.x * 256 + threadIdx.x;
  int lane = threadIdx.x & 63;
  int wid = threadIdx.x >> 6;
  bool marked = (slotmap[cell] == -2);
  unsigned long long mask = __ballot(marked);
  if (lane == 0) wbase[wid] = __popcll(mask);
  __syncthreads();
  if (threadIdx.x == 0) {
    int tot = wbase[0] + wbase[1] + wbase[2] + wbase[3];
    int base = tot ? atomicAdd(nC, tot) : 0;
    for (int i = 0; i < 4; ++i) { int c = wbase[i]; wbase[i] = base; base += c; }
  }
  __syncthreads();
  if (marked) {
    int rank = __popcll(mask & ((1ull << lane) - 1ull));
    int s = wbase[wid] + rank;
    slotmap[cell] = s;
    slotmapT[(cell & 511) * 512 + (cell >> 9)] = s;
    cells[s] = cell;
  }
}

// ---------------- K7: nb_feat scatter-add into COMPACT Tc (2 edges/block) ----
__global__ __launch_bounds__(192) void k_scatterT(
    const int* __restrict__ nb_edge, const int* __restrict__ slotmap,
    const float* __restrict__ coord_diff, const float* __restrict__ efn,
    float* __restrict__ Tc) {
  int t = threadIdx.x;
  int sub = (t >= 96) ? 1 : 0;
  int c = t - sub * 96;
  int m = blockIdx.x * 2 + sub;
  int a = nb_edge[m], b = nb_edge[MM + m];
  int s = slotmap[a * 512 + b];
  float val;
  if (c < 32) {
    float vtv = coord_diff[a * 3 + 0] * coord_diff[b * 3 + 0]
              + coord_diff[a * 3 + 1] * coord_diff[b * 3 + 1]
              + coord_diff[a * 3 + 2] * coord_diff[b * 3 + 2];
    int i = c >> 1;
    float ang = vtv * 16.0f * __expf(-0.57564627324851143f * (float)i);
    val = (c & 1) ? cosf(ang) : sinf(ang);
  } else {
    int f = c - 32;
    val = efn[a * 64 + f] * efn[b * 64 + f];
  }
  atomicAdd(&Tc[s * 96 + c], val);
}

// ------- K_GEMM1: [16384 x 96] @ [96 x 384] MFMA, tiles 128x128 --------------
__global__ __launch_bounds__(256) void k_gemm1(
    const int* __restrict__ nC, const float* __restrict__ Tc,
    const __hip_bfloat16* __restrict__ WBT,
    const float* __restrict__ b11, const float* __restrict__ b21,
    float* __restrict__ TWc, __hip_bfloat16* __restrict__ H1,
    __hip_bfloat16* __restrict__ H2) {
  __shared__ short As[128 * 104];
  __shared__ short Bs[128 * 104];
  int i0 = blockIdx.x * 128;
  int nt = blockIdx.y;
  if (i0 >= *nC) return;
  int t = threadIdx.x;
  int w = t >> 6, lane = t & 63;
  int wy = w >> 1, wx = w & 1;
  int q = lane >> 4, l15 = lane & 15;
  const short* Bp = (const short*)WBT + nt * 128 * 96;
  for (int idx = t; idx < 1536; idx += 256) {
    int row = idx / 12, seg = idx % 12;
    const float4* tp = (const float4*)&Tc[(i0 + row) * 96 + seg * 8];
    float4 a0 = tp[0], a1 = tp[1];
    short8v cv = {bf16bits(a0.x), bf16bits(a0.y), bf16bits(a0.z), bf16bits(a0.w),
                  bf16bits(a1.x), bf16bits(a1.y), bf16bits(a1.z), bf16bits(a1.w)};
    *(short8v*)&As[row * 104 + seg * 8] = cv;
    *(short8v*)&Bs[row * 104 + seg * 8] = *(const short8v*)&Bp[row * 96 + seg * 8];
  }
  __syncthreads();
  v4f acc[4][4];
#pragma unroll
  for (int yi = 0; yi < 4; ++yi)
#pragma unroll
    for (int xj = 0; xj < 4; ++xj) acc[yi][xj] = (v4f){0.f, 0.f, 0.f, 0.f};
#pragma unroll
  for (int k0 = 0; k0 < 96; k0 += 32) {
    short8v af[4], bf[4];
#pragma unroll
    for (int x = 0; x < 4; ++x) {
      af[x] = *(const short8v*)&As[(wy * 64 + x * 16 + l15) * 104 + k0 + q * 8];
      bf[x] = *(const short8v*)&Bs[(wx * 64 + x * 16 + l15) * 104 + k0 + q * 8];
    }
#pragma unroll
    for (int yi = 0; yi < 4; ++yi)
#pragma unroll
      for (int xj = 0; xj < 4; ++xj)
        acc[yi][xj] = __builtin_amdgcn_mfma_f32_16x16x32_bf16(af[yi], bf[xj], acc[yi][xj], 0, 0, 0);
  }
  // C layout [m89]: row = q*4+r, col = l15
#pragma unroll
  for (int yi = 0; yi < 4; ++yi)
#pragma unroll
    for (int r = 0; r < 4; ++r) {
      int s = i0 + wy * 64 + yi * 16 + q * 4 + r;
#pragma unroll
      for (int xj = 0; xj < 4; ++xj) {
        int j = wx * 64 + xj * 16 + l15;
        float val = acc[yi][xj][r];
        if (nt == 0) TWc[s * 128 + j] = val;
        else if (nt == 1) H1[s * 128 + j] = __float2bfloat16(silu_f(val + b11[j]));
        else H2[s * 128 + j] = __float2bfloat16(silu_f(val + b21[j]));
      }
    }
}

// ------- K_GEMM2: [16384 x 128] @ [128 x 64] MFMA, tiles 128x64 --------------
__global__ __launch_bounds__(256) void k_gemm2(
    const int* __restrict__ nC, const int* __restrict__ cells,
    const __hip_bfloat16* __restrict__ H1, const __hip_bfloat16* __restrict__ H2,
    const __hip_bfloat16* __restrict__ W2T,
    const float* __restrict__ b12, const float* __restrict__ b22,
    const float* __restrict__ c1, const float* __restrict__ c2,
    __hip_bfloat16* __restrict__ Dc1, __hip_bfloat16* __restrict__ Dc2,
    float* __restrict__ A, float* __restrict__ B) {
  __shared__ short Hs[128 * 136];   // 34,816 B
  __shared__ short Wsh[64 * 136];   // 17,408 B
  __shared__ int cellL[128];
  int i0 = blockIdx.x * 128;
  int which = blockIdx.y;
  int nc = *nC;
  if (i0 >= nc) return;
  int t = threadIdx.x;
  int w = t >> 6, lane = t & 63;
  int q = lane >> 4, l15 = lane & 15;
  const short* Hp = (const short*)(which ? H2 : H1);
  const short* Wp = (const short*)W2T + which * 64 * 128;
  for (int idx = t; idx < 2048; idx += 256) {
    int row = idx >> 4, seg = idx & 15;
    *(short8v*)&Hs[row * 136 + seg * 8] = *(const short8v*)&Hp[(i0 + row) * 128 + seg * 8];
  }
  for (int idx = t; idx < 1024; idx += 256) {
    int row = idx >> 4, seg = idx & 15;
    *(short8v*)&Wsh[row * 136 + seg * 8] = *(const short8v*)&Wp[row * 128 + seg * 8];
  }
  if (t < 128) cellL[t] = (i0 + t < nc) ? cells[i0 + t] : 0;
  __syncthreads();
  v4f acc[2][4];
#pragma unroll
  for (int y = 0; y < 2; ++y)
#pragma unroll
    for (int xj = 0; xj < 4; ++xj) acc[y][xj] = (v4f){0.f, 0.f, 0.f, 0.f};
#pragma unroll
  for (int k0 = 0; k0 < 128; k0 += 32) {
    short8v af[2], bf[4];
#pragma unroll
    for (int y = 0; y < 2; ++y)
      af[y] = *(const short8v*)&Hs[(w * 32 + y * 16 + l15) * 136 + k0 + q * 8];
#pragma unroll
    for (int xj = 0; xj < 4; ++xj)
      bf[xj] = *(const short8v*)&Wsh[(xj * 16 + l15) * 136 + k0 + q * 8];
#pragma unroll
    for (int y = 0; y < 2; ++y)
#pragma unroll
      for (int xj = 0; xj < 4; ++xj)
        acc[y][xj] = __builtin_amdgcn_mfma_f32_16x16x32_bf16(af[y], bf[xj], acc[y][xj], 0, 0, 0);
  }
  const float* bias = which ? b22 : b12;
  const float* cc = which ? c2 : c1;
#pragma unroll
  for (int y = 0; y < 2; ++y)
#pragma unroll
    for (int r = 0; r < 4; ++r) {
      int lrow = w * 32 + y * 16 + q * 4 + r;
      int s = i0 + lrow;
      if (s >= nc) continue;
      int cell = cellL[lrow];
      int idx = which ? (cell & 511) : (cell >> 9);
#pragma unroll
      for (int xj = 0; xj < 4; ++xj) {
        int hh = xj * 16 + l15;
        float d = acc[y][xj][r] + bias[hh] - cc[hh];
        if (which) { atomicAdd(&B[idx * 64 + hh], d); Dc2[s * 64 + hh] = __float2bfloat16(d); }
        else       { atomicAdd(&A[idx * 64 + hh], d); Dc1[s * 64 + hh] = __float2bfloat16(d); }
      }
    }
}

// ------- K_DENS_UV: fused {densify planes, u/v vectors} ----------------------
__global__ __launch_bounds__(128) void k_dens_uv(
    const int* __restrict__ slotmap, const int* __restrict__ slotmapT,
    const __hip_bfloat16* __restrict__ Dc1, const __hip_bfloat16* __restrict__ Dc2,
    __hip_bfloat16* __restrict__ D1d, __hip_bfloat16* __restrict__ D2dT,
    const float* __restrict__ A, const float* __restrict__ B,
    const float* __restrict__ c1, const float* __restrict__ c2,
    const float* __restrict__ p3w1, const float* __restrict__ p3b1,
    float* __restrict__ u, float* __restrict__ v) {
  __shared__ float vec[64];
  int b = blockIdx.x, t = threadIdx.x;
  if (b < 65536) {
    int which = b >> 15, bb = b & 32767;
    int f = bb >> 9, row = bb & 511;
    const int* sm = which ? &slotmapT[row * 512] : &slotmap[row * 512];
    const unsigned short* Dc = (const unsigned short*)(which ? Dc2 : Dc1);
    unsigned short* dst = (unsigned short*)(which ? &D2dT[(f * 512 + row) * 512]
                                                  : &D1d[(f * 512 + row) * 512]);
    int4 s4 = *(const int4*)&sm[t * 4];
    ushort4 o;
    o.x = (s4.x >= 0) ? Dc[s4.x * 64 + f] : 0;
    o.y = (s4.y >= 0) ? Dc[s4.y * 64 + f] : 0;
    o.z = (s4.z >= 0) ? Dc[s4.z * 64 + f] : 0;
    o.w = (s4.w >= 0) ? Dc[s4.w * 64 + f] : 0;
    *(ushort4*)&dst[t * 4] = o;
  } else {
    int e = b - 65536;
    int i = e >> 1, y = e & 1;
    if (t < 64)
      vec[t] = (y == 0) ? (512.0f * c1[t] * c2[t] + c2[t] * A[i * 64 + t])
                        : (c1[t] * B[i * 64 + t]);
    __syncthreads();
    float a = (y == 0) ? p3b1[t] : 0.f;
    for (int f = 0; f < 64; ++f) a += vec[f] * p3w1[(96 + f) * 128 + t];
    (y == 0 ? u : v)[i * 128 + t] = a;
  }
}

// ---------------- K11b: batched plane GEMM S_f = A_f * B_f (MFMA) ------------
// XCD-aware bijective swizzle (proven v11): each XCD owns 8 whole planes.
__global__ __launch_bounds__(256) void k_einsum_mfma(
    const __hip_bfloat16* __restrict__ D1d,
    const __hip_bfloat16* __restrict__ D2dT,
    __hip_bfloat16* __restrict__ S_fij) {
  __shared__ short As[128 * 40];
  __shared__ short Bs[128 * 40];
  int braw = blockIdx.x;
  int b = (braw & 7) * 128 + (braw >> 3);   // bijective XCD swizzle (1024 = 8*128)
  int f = b >> 4;
  int i0 = ((b >> 2) & 3) * 128, j0 = (b & 3) * 128;
  int t = threadIdx.x;
  int w = t >> 6, lane = t & 63;
  int wy = w >> 1, wx = w & 1;
  int q = lane >> 4, l15 = lane & 15;
  const short* Ap = (const short*)D1d + f * 262144;
  const short* Bp = (const short*)D2dT + f * 262144;
  int row = t >> 1, seg = t & 1;   // staging: 128 rows x 2 segments of 16
  v4f acc[4][4];
#pragma unroll
  for (int yi = 0; yi < 4; ++yi)
#pragma unroll
    for (int xj = 0; xj < 4; ++xj) acc[yi][xj] = (v4f){0.f, 0.f, 0.f, 0.f};
  for (int k0 = 0; k0 < 512; k0 += 32) {
    __syncthreads();
    const short8v* ga = (const short8v*)&Ap[(i0 + row) * 512 + k0 + seg * 16];
    const short8v* gb = (const short8v*)&Bp[(j0 + row) * 512 + k0 + seg * 16];
    *(short8v*)&As[row * 40 + seg * 16] = ga[0];
    *(short8v*)&As[row * 40 + seg * 16 + 8] = ga[1];
    *(short8v*)&Bs[row * 40 + seg * 16] = gb[0];
    *(short8v*)&Bs[row * 40 + seg * 16 + 8] = gb[1];
    __syncthreads();
    short8v af[4], bf[4];
#pragma unroll
    for (int x = 0; x < 4; ++x) {
      af[x] = *(const short8v*)&As[(wy * 64 + x * 16 + l15) * 40 + q * 8];
      bf[x] = *(const short8v*)&Bs[(wx * 64 + x * 16 + l15) * 40 + q * 8];
    }
#pragma unroll
    for (int yi = 0; yi < 4; ++yi)
#pragma unroll
      for (int xj = 0; xj < 4; ++xj)
        acc[yi][xj] = __builtin_amdgcn_mfma_f32_16x16x32_bf16(af[yi], bf[xj], acc[yi][xj], 0, 0, 0);
  }
  // C layout: col j = l15, row i = q*4 + r  [m89-verified]
#pragma unroll
  for (int yi = 0; yi < 4; ++yi)
#pragma unroll
    for (int r = 0; r < 4; ++r) {
      int irow = i0 + wy * 64 + yi * 16 + q * 4 + r;
#pragma unroll
      for (int xj = 0; xj < 4; ++xj)
        S_fij[(f * 512 + irow) * 512 + j0 + wx * 64 + xj * 16 + l15] =
            __float2bfloat16(acc[yi][xj][r]);
    }
}

// ---------------- K11c: transpose S_fij [64][262144] -> S [262144][64] -------
__global__ __launch_bounds__(256) void k_transpose(
    const __hip_bfloat16* __restrict__ S_fij, __hip_bfloat16* __restrict__ S) {
  __shared__ short lds[64 * 72];
  int t = threadIdx.x;
  int ij0 = blockIdx.x * 64;
  const short* src = (const short*)S_fij;
#pragma unroll
  for (int p = 0; p < 2; ++p) {
    int f = p * 32 + (t >> 3), seg = t & 7;
    short8v ga = *(const short8v*)&src[f * 262144 + ij0 + seg * 8];
    int fgrp = f >> 3, flo = f & 7;
#pragma unroll
    for (int k = 0; k < 8; ++k) {
      int ij = seg * 8 + k;
      int swz = (fgrp ^ (ij & 7) ^ ((ij >> 3) & 7)) & 7;
      lds[ij * 72 + swz * 8 + flo] = ga[k];
    }
  }
  __syncthreads();
  short* dst = (short*)S;
#pragma unroll
  for (int p = 0; p < 2; ++p) {
    int ij = p * 32 + (t >> 3), fseg = t & 7;
    int swz = (fseg ^ (ij & 7) ^ ((ij >> 3) & 7)) & 7;
    short8v val = *(const short8v*)&lds[ij * 72 + swz * 8];
    *(short8v*)&dst[(ij0 + ij) * 64 + fseg * 8] = val;
  }
}

// ------- K12: dense MFMA z = S@Wt + u[i]+v[j], silu, row/col/diag reduce -----
// R15-proven: plain row_part/col_part partial stores (v13's direct atomics
// into corr_row/col were 32-way same-address contention: k_tout 41->56us).
__global__ __launch_bounds__(256) void k_tout_mfma(
    const __hip_bfloat16* __restrict__ S, const float* __restrict__ u,
    const float* __restrict__ v, const __hip_bfloat16* __restrict__ Wt,
    float* __restrict__ row_part, float* __restrict__ col_part,
    float* __restrict__ diag_silu) {
  __shared__ __hip_bfloat16 WtL[128 * 72];         // 18,432 B
  __shared__ __hip_bfloat16 uvL[4096];             // 8,192 B
  __shared__ __hip_bfloat16 colbuf[4][16][140];    // 17,920 B
  int t = threadIdx.x;
  int w = t >> 6, lane = t & 63;
  int q = lane >> 4, l15 = lane & 15;
  int bi = blockIdx.x >> 5, bj = blockIdx.x & 31;
  int i0 = bi * 16, j0 = bj * 16;
  for (int e = t; e < 4096; e += 256) {
    int row = e >> 5, c2 = e & 31;
    ((unsigned*)WtL)[row * 36 + c2] = ((const unsigned*)Wt)[row * 32 + c2];
  }
  for (int e = t; e < 2048; e += 256)
    uvL[e] = __float2bfloat16(u[(i0 + (e >> 7)) * 128 + (e & 127)]);
  for (int e = t; e < 2048; e += 256)
    uvL[2048 + e] = __float2bfloat16(v[(j0 + (e >> 7)) * 128 + (e & 127)]);
  short8v a[4][2];
#pragma unroll
  for (int mt = 0; mt < 4; ++mt) {
    const short8v* sp =
        (const short8v*)&S[((i0 + w * 4 + mt) * 512 + j0 + l15) * 64];
    a[mt][0] = sp[q];
    a[mt][1] = sp[4 + q];
  }
  __syncthreads();
#pragma unroll
  for (int half = 0; half < 2; ++half) {
    v4f acc[4][4];
#pragma unroll
    for (int mt = 0; mt < 4; ++mt)
#pragma unroll
      for (int n4 = 0; n4 < 4; ++n4) {
        int nt = half * 4 + n4;
        const short8v* b0 = (const short8v*)&WtL[(nt * 16 + l15) * 72 + q * 8];
        const short8v* b1 = (const short8v*)&WtL[(nt * 16 + l15) * 72 + 32 + q * 8];
        v4f c = {0.f, 0.f, 0.f, 0.f};
        c = __builtin_amdgcn_mfma_f32_16x16x32_bf16(a[mt][0], *b0, c, 0, 0, 0);
        c = __builtin_amdgcn_mfma_f32_16x16x32_bf16(a[mt][1], *b1, c, 0, 0, 0);
        acc[mt][n4] = c;
      }
#pragma unroll
    for (int n4 = 0; n4 < 4; ++n4) {
      int nt = half * 4 + n4;
      int hh = nt * 16 + l15;
      float uu[4];
#pragma unroll
      for (int mt = 0; mt < 4; ++mt)
        uu[mt] = __bfloat162float(uvL[(w * 4 + mt) * 128 + hh]);
      float rs[4] = {0.f, 0.f, 0.f, 0.f};
#pragma unroll
      for (int r = 0; r < 4; ++r) {
        int jL = q * 4 + r;
        float cs = 0.f;
        float vv = __bfloat162float(uvL[2048 + jL * 128 + hh]);
#pragma unroll
        for (int mt = 0; mt < 4; ++mt) {
          int iL = w * 4 + mt;
          float sv = silu_fast(acc[mt][n4][r] + uu[mt] + vv);
          rs[mt] += sv;
          cs += sv;
          if (bi == bj && iL == jL) diag_silu[(i0 + iL) * 128 + hh] = sv;
        }
        colbuf[w][jL][hh] = __float2bfloat16(cs);
      }
#pragma unroll
      for (int mt = 0; mt < 4; ++mt) {
        float rsum = rs[mt];
        rsum += __shfl_xor(rsum, 16);
        rsum += __shfl_xor(rsum, 32);
        if (q == 0)
          row_part[(bj * 512 + i0 + w * 4 + mt) * 128 + hh] = rsum;
      }
    }
  }
  __syncthreads();
  for (int e = t; e < 2048; e += 256) {
    int jL = e >> 7, hh = e & 127;
    float acc4 = __bfloat162float(colbuf[0][jL][hh]) + __bfloat162float(colbuf[1][jL][hh]) +
                 __bfloat162float(colbuf[2][jL][hh]) + __bfloat162float(colbuf[3][jL][hh]);
    col_part[(bi * 512 + j0 + jL) * 128 + hh] = acc4;
  }
}

// ------- K_CORR: sparse TW correction at touched cells (standalone) ----------
__global__ __launch_bounds__(128) void k_corr(
    const int* __restrict__ cells, const int* __restrict__ nC,
    const __hip_bfloat16* __restrict__ S, const float* __restrict__ u,
    const float* __restrict__ v, const float* __restrict__ TWc,
    const __hip_bfloat16* __restrict__ Wt,
    float* __restrict__ corr_row, float* __restrict__ corr_col,
    float* __restrict__ corr_diag) {
  __shared__ float sf[64];
  int s = blockIdx.x;
  if (s >= *nC) return;
  int t = threadIdx.x;
  int cell = cells[s];
  int ai = cell >> 9, bj = cell & 511;
  if (t < 64) sf[t] = __bfloat162float(S[(ai * 512 + bj) * 64 + t]);
  __syncthreads();
  float acc = 0.f;
  const __hip_bfloat16* wr = &Wt[t * 64];
  for (int f = 0; f < 64; ++f) acc += sf[f] * __bfloat162float(wr[f]);
  float z0 = acc + u[ai * 128 + t] + v[bj * 128 + t];
  float zc = z0 + TWc[s * 128 + t];
  float d = silu_fast(zc) - silu_fast(z0);
  atomicAdd(&corr_row[ai * 128 + t], d);
  atomicAdd(&corr_col[bj * 128 + t], d);
  if (ai == bj) atomicAdd(&corr_diag[ai * 128 + t], d);
}

// ------- K_TOUT2F: fused {32-partial reduce + corr, p3 layer-2, tot/tr} ------
__global__ __launch_bounds__(128) void k_tout2f(
    const float* __restrict__ diag_silu, const float* __restrict__ row_part,
    const float* __restrict__ col_part,
    const float* __restrict__ corr_row, const float* __restrict__ corr_col,
    const float* __restrict__ corr_diag,
    const float* __restrict__ w2, const float* __restrict__ b2,
    float* __restrict__ diag_T, float* __restrict__ row_T, float* __restrict__ col_T,
    float* __restrict__ tot, float* __restrict__ tr) {
  __shared__ float in[128];
  int e = blockIdx.x, which = blockIdx.y, t = threadIdx.x;
  float a;
  if (which == 0) {
    a = diag_silu[e * 128 + t] + corr_diag[e * 128 + t];
  } else {
    const float* src = (which == 1) ? row_part : col_part;
    a = (which == 1) ? corr_row[e * 128 + t] : corr_col[e * 128 + t];
    for (int p = 0; p < 32; ++p) a += src[(p * 512 + e) * 128 + t];
  }
  in[t] = a;
  __syncthreads();
  if (t < 64) {
    float o = 0.f;
    for (int k = 0; k < 128; ++k) o += in[k] * w2[k * 64 + t];
    float val = o + b2[t] * ((which == 0) ? 1.0f : 512.0f);
    if (which == 0)      { diag_T[e * 64 + t] = val; atomicAdd(&tr[t], val); }
    else if (which == 1) { row_T[e * 64 + t] = val; atomicAdd(&tot[t], val); }
    else                 { col_T[e * 64 + t] = val; }
  }
}

// ------- K_NBT1_EDGE: fused {IGN linear, coord weight, seg/cnt/nb_t0} --------
__global__ __launch_bounds__(128) void k_nbt1_edge(
    const float* __restrict__ diag_T, const float* __restrict__ row_T,
    const float* __restrict__ col_T, const float* __restrict__ tot,
    const float* __restrict__ tr,
    const float* __restrict__ gw, const float* __restrict__ gb,
    const int* __restrict__ edges, const float* __restrict__ coord_diff,
    const float* __restrict__ edge_attr,
    const float* __restrict__ cw1, const float* __restrict__ cb1,
    const float* __restrict__ cw2,
    float* __restrict__ seg, float* __restrict__ cnt, float* __restrict__ nb_t0,
    float* __restrict__ out_ea) {
  __shared__ float in[320];
  __shared__ float nbt[64];
  __shared__ float red[128];
  int e = blockIdx.x, t = threadIdx.x;
  if (t < 64) {
    in[t] = diag_T[e * 64 + t]; in[64 + t] = row_T[e * 64 + t];
    in[128 + t] = col_T[e * 64 + t]; in[192 + t] = tot[t]; in[256 + t] = tr[t];
  }
  __syncthreads();
  if (t < 64) {
    float a = gb[t];
    for (int k = 0; k < 320; ++k) a += in[k] * gw[k * 64 + t];
    nbt[t] = a;
  }
  __syncthreads();
  float a = cb1[t];
  for (int k = 0; k < 64; ++k) a += nbt[k] * cw1[k * 128 + t];
  red[t] = silu_f(a) * cw2[t];
  __syncthreads();
  for (int s2 = 64; s2 > 0; s2 >>= 1) {
    if (t < s2) red[t] += red[t + s2];
    __syncthreads();
  }
  float w = red[0];
  int r = edges[e];
  if (t < 3) atomicAdd(&seg[r * 3 + t], coord_diff[e * 3 + t] * w);
  if (t == 64) atomicAdd(&cnt[r], 1.0f);
  if (t < 64) atomicAdd(&nb_t0[r * 64 + t], nbt[t]);
  if (t < 4) out_ea[e * 4 + t] = edge_attr[e * 4 + t];
}

// ---------------- K18: x_new and h_new ---------------------------------------
__global__ __launch_bounds__(128) void k_node_out(
    const float* __restrict__ h, const float* __restrict__ x,
    const float* __restrict__ seg, const float* __restrict__ cnt,
    const float* __restrict__ nb_t0,
    const float* __restrict__ w1, const float* __restrict__ b1,
    const float* __restrict__ w2, const float* __restrict__ b2,
    float* __restrict__ out_h, float* __restrict__ out_x) {
  __shared__ float in[64];
  __shared__ float hs[128];
  int n = blockIdx.x, t = threadIdx.x;
  if (t < 3) {
    float c = cnt[n]; if (c < 1.f) c = 1.f;
    out_x[n * 3 + t] = x[n * 3 + t] + seg[n * 3 + t] / c;
  }
  if (t < 64) in[t] = nb_t0[n * 64 + t];
  __syncthreads();
  float a = b1[t];
  for (int k = 0; k < 64; ++k) a += in[k] * w1[k * 128 + t];
  hs[t] = silu_f(a);
  __syncthreads();
  if (t < 64) {
    float o = b2[t];
    for (int k = 0; k < 128; ++k) o += hs[k] * w2[k * 64 + t];
    out_h[n * 64 + t] = h[n * 64 + t] + o;
  }
}

extern "C" void kernel_launch(void* const* d_in, const int* in_sizes, int n_in,
                              void* d_out, int out_size, void* d_ws, size_t ws_size,
                              hipStream_t stream) {
  (void)in_sizes; (void)n_in; (void)out_size; (void)ws_size;
  const float* h  = (const float*)d_in[0];
  const float* x  = (const float*)d_in[1];
  const int* edges   = (const int*)d_in[2];
  const int* nb_edge = (const int*)d_in[3];
  const float* edge_attr = (const float*)d_in[4];
  const float* ew1 = (const float*)d_in[6],  *eb1 = (const float*)d_in[7];
  const float* ew2 = (const float*)d_in[8],  *eb2 = (const float*)d_in[9];
  const float* p1w1 = (const float*)d_in[10], *p1b1 = (const float*)d_in[11];
  const float* p1w2 = (const float*)d_in[12], *p1b2 = (const float*)d_in[13];
  const float* p2w1 = (const float*)d_in[14], *p2b1 = (const float*)d_in[15];
  const float* p2w2 = (const float*)d_in[16], *p2b2 = (const float*)d_in[17];
  const float* p3w1 = (const float*)d_in[18], *p3b1 = (const float*)d_in[19];
  const float* p3w2 = (const float*)d_in[20], *p3b2 = (const float*)d_in[21];
  const float* ignw = (const float*)d_in[22], *ignb = (const float*)d_in[23];
  const float* cw1 = (const float*)d_in[24], *cb1 = (const float*)d_in[25];
  const float* cw2 = (const float*)d_in[26];
  const float* ndw1 = (const float*)d_in[27], *ndb1 = (const float*)d_in[28];
  const float* ndw2 = (const float*)d_in[29], *ndb2 = (const float*)d_in[30];

  // ---- workspace layout (~157.9 MB) ----
  char* ws = (char*)d_ws;
  __hip_bfloat16* D1d  = (__hip_bfloat16*)(ws + 0);          // [64][512][512] = 33,554,432 B
  __hip_bfloat16* S    = (__hip_bfloat16*)(ws + 0);          // cell-major S aliases dead D1d
  __hip_bfloat16* D2dT = (__hip_bfloat16*)(ws + 33554432);   // 33,554,432 B
  __hip_bfloat16* S_fij = (__hip_bfloat16*)(ws + 67108864);  // 33,554,432 B
  // GEMM scratch aliases the S_fij region (dead until k_einsum):
  __hip_bfloat16* H1  = (__hip_bfloat16*)(ws + 70254592);    // [16384][128] = 4,194,304 B
  __hip_bfloat16* H2  = (__hip_bfloat16*)(ws + 74448896);    // 4,194,304 B
  __hip_bfloat16* WBT = (__hip_bfloat16*)(ws + 78643200);    // [384][96] = 73,728 B
  __hip_bfloat16* W2T = (__hip_bfloat16*)(ws + 78716928);    // [2][64][128] = 32,768 B
  float* row_part = (float*)(ws + 100663296);                // [32][512][128] = 8,388,608 B
  float* col_part = (float*)(ws + 117440512);                // [32][512][128]
  // ---- single zero block [134,217,728 .. 141,435,408), zeroed by k_front ----
  float* Tc    = (float*)(ws + 134217728);                   // [16384][96] = 6,291,456 B
  int*   nC    = (int*)(ws + 140509184);                     // 1 int (+pad to 16)
  float* A     = (float*)(ws + 140509200);                   // 32768 floats
  float* B     = (float*)(ws + 140640272);                   // 32768 floats
  float* seg   = (float*)(ws + 140771344);                   // 1536 floats
  float* cnt   = (float*)(ws + 140777488);                   // 512 floats
  float* nb_t0 = (float*)(ws + 140779536);                   // 32768 floats -> 140,910,608
  float* tot   = (float*)(ws + 140910608);                   // 64 floats
  float* tr    = (float*)(ws + 140910864);                   // 64 floats -> 140,911,120
  float* corr_row = (float*)(ws + 140911120);                // [512][128] -> 141,173,264
  float* corr_col = (float*)(ws + 141173264);                // [512][128] -> 141,435,408
  // ---- 0xFF block: slotmap + slotmapT (2 MB contiguous) ----
  int*   slotmap  = (int*)(ws + 141435904);                  // 262144 ints
  int*   slotmapT = (int*)(ws + 142484480);                  // 262144 ints
  // ---- rest ----
  int*   cells    = (int*)(ws + 143533056);                  // 16384 ints
  __hip_bfloat16* Dc1 = (__hip_bfloat16*)(ws + 143598592);   // [16384][64] = 2,097,152 B
  __hip_bfloat16* Dc2 = (__hip_bfloat16*)(ws + 145695744);   // 2,097,152 B
  float* TWc      = (float*)(ws + 147792896);                // [16384][128]
  float* c1       = (float*)(ws + 156181504);                // 64
  float* c2       = (float*)(ws + 156181760);                // 64
  float* u        = (float*)(ws + 156182016);                // [512][128]
  float* v        = (float*)(ws + 156444160);                // [512][128]
  float* coord_diff  = (float*)(ws + 156706304);             // [512][3]
  float* efn         = (float*)(ws + 156712448);             // [512][64]
  float* diag_silu   = (float*)(ws + 156843520);             // [512][128]
  float* diag_T      = (float*)(ws + 157105664);             // [512][64]
  float* row_T       = (float*)(ws + 157236736);
  float* col_T       = (float*)(ws + 157367808);
  __hip_bfloat16* Wt  = (__hip_bfloat16*)(ws + 157629952);   // [128][64] -> 157,646,336
  float* corr_diag   = (float*)(ws + 157646336);             // [512][128] (zeroed by k_front)

  float* out_h  = (float*)d_out;
  float* out_x  = out_h + 512 * 64;
  float* out_ea = out_x + 512 * 3;

  hipMemsetAsync(slotmap, 0xFF, 2097152, stream);            // slotmap + slotmapT = -1

  k_front<<<5158, 128, 0, stream>>>(h, x, edges, nb_edge,
                                    ew1, eb1, ew2, eb2,
                                    p1w1, p1b1, p1w2, p1b2,
                                    p2w1, p2b1, p2w2, p2b2, p3w1,
                                    coord_diff, efn, c1, c2, Wt, slotmap,
                                    WBT, W2T, corr_diag, ws + 134217728);
  k_compact<<<1024, 256, 0, stream>>>(slotmap, slotmapT, cells, nC);
  k_scatterT<<<8192, 192, 0, stream>>>(nb_edge, slotmap, coord_diff, efn, Tc);
  k_gemm1<<<dim3(128, 3), 256, 0, stream>>>(nC, Tc, WBT, p1b1, p2b1,
                                            TWc, H1, H2);
  k_gemm2<<<dim3(128, 2), 256, 0, stream>>>(nC, cells, H1, H2, W2T,
                                            p1b2, p2b2, c1, c2,
                                            Dc1, Dc2, A, B);
  k_dens_uv<<<66560, 128, 0, stream>>>(slotmap, slotmapT, Dc1, Dc2, D1d, D2dT,
                                       A, B, c1, c2, p3w1, p3b1, u, v);
  k_einsum_mfma<<<1024, 256, 0, stream>>>(D1d, D2dT, S_fij);
  k_transpose<<<4096, 256, 0, stream>>>(S_fij, S);
  k_tout_mfma<<<1024, 256, 0, stream>>>(S, u, v, Wt,
                                        row_part, col_part, diag_silu);
  k_corr<<<16384, 128, 0, stream>>>(cells, nC, S, u, v, TWc, Wt,
                                    corr_row, corr_col, corr_diag);
  k_tout2f<<<dim3(512, 3), 128, 0, stream>>>(diag_silu, row_part, col_part,
                                             corr_row, corr_col, corr_diag,
                                             p3w2, p3b2, diag_T, row_T, col_T,
                                             tot, tr);
  k_nbt1_edge<<<512, 128, 0, stream>>>(diag_T, row_T, col_T, tot, tr,
                                       ignw, ignb, edges, coord_diff, edge_attr,
                                       cw1, cb1, cw2, seg, cnt, nb_t0, out_ea);
  k_node_out<<<512, 128, 0, stream>>>(h, x, seg, cnt, nb_t0,
                                      ndw1, ndb1, ndw2, ndb2, out_h, out_x);
}